// Round 3
// baseline (7989.068 us; speedup 1.0000x reference)
//
#include <hip/hip_runtime.h>
#include <hip/hip_bf16.h>

#define B_ 128
#define S_ 256
#define I_ 512
#define H_ 1024

typedef float  f32x4  __attribute__((ext_vector_type(4)));
typedef __bf16 bf16x8 __attribute__((ext_vector_type(8)));
typedef unsigned short u16x8 __attribute__((ext_vector_type(8)));

__device__ __forceinline__ unsigned short f2bf(float f) {
    unsigned u = __float_as_uint(f);
    unsigned r = (u + 0x7fffu + ((u >> 16) & 1u)) >> 16;   // RNE
    return (unsigned short)r;
}
__device__ __forceinline__ float bf2f(unsigned short s) {
    return __uint_as_float(((unsigned)s) << 16);
}

// ---------------------------------------------------------------------------
// Column mapping (4 h-cols per p, 256 p-groups): B/C tile col c:
//   c 0-3  -> r-gate  row p*4+c
//   c 4-7  -> z-gate  row H + p*4+(c-4)
//   c 8-11 -> n-gate  row 2H + p*4+(c-8)
//   c 12-15 -> zero pad
// ---------------------------------------------------------------------------

// Pack W_ih [3H, I] into B-fragment order: [p 256][ks 16][lane 64][8]
__global__ __launch_bounds__(256) void pack_wih(const float* __restrict__ W,
                                                unsigned short* __restrict__ out) {
    int gid = blockIdx.x * 256 + threadIdx.x;        // 262144 total
    int lane = gid & 63, ks = (gid >> 6) & 15, p = gid >> 10;
    int c = lane & 15, quad = lane >> 4;
    int k = ks * 32 + quad * 8;
    int n = 0; bool valid = true;
    if (c < 4) n = p * 4 + c;
    else if (c < 8) n = H_ + p * 4 + (c - 4);
    else if (c < 12) n = 2 * H_ + p * 4 + (c - 8);
    else valid = false;
    const float* src = W + (size_t)n * I_ + k;
    u16x8 v;
#pragma unroll
    for (int jj = 0; jj < 8; jj++) v[jj] = valid ? f2bf(src[jj]) : (unsigned short)0;
    *(u16x8*)(out + (size_t)gid * 8) = v;
}

// Pack W_hh [3H, H] hi/lo into B-fragment order: [p 256][ks 32][lane 64][8]
__global__ __launch_bounds__(256) void pack_whh(const float* __restrict__ W,
                                                unsigned short* __restrict__ hi,
                                                unsigned short* __restrict__ lo) {
    int gid = blockIdx.x * 256 + threadIdx.x;        // 524288 total
    int lane = gid & 63, ks = (gid >> 6) & 31, p = gid >> 11;
    int c = lane & 15, quad = lane >> 4;
    int k = ks * 32 + quad * 8;
    int n = 0; bool valid = true;
    if (c < 4) n = p * 4 + c;
    else if (c < 8) n = H_ + p * 4 + (c - 4);
    else if (c < 12) n = 2 * H_ + p * 4 + (c - 8);
    else valid = false;
    const float* src = W + (size_t)n * H_ + k;
    u16x8 vh, vl;
#pragma unroll
    for (int jj = 0; jj < 8; jj++) {
        float f = valid ? src[jj] : 0.f;
        unsigned short h16 = f2bf(f);
        unsigned short l16 = f2bf(f - bf2f(h16));
        vh[jj] = valid ? h16 : (unsigned short)0;
        vl[jj] = valid ? l16 : (unsigned short)0;
    }
    *(u16x8*)(hi + (size_t)gid * 8) = vh;
    *(u16x8*)(lo + (size_t)gid * 8) = vl;
}

// Pack x into A-fragment bf16 layout via LDS transpose: [t][m 8][ks 16][lane 64][8]
__global__ __launch_bounds__(256) void pack_x(const float* __restrict__ x,
                                              unsigned short* __restrict__ Gx) {
    int bid = blockIdx.x;                 // 2048 = 256 t * 8 m
    int t = bid >> 3, m = bid & 7;
    int tid = threadIdx.x;
    __shared__ unsigned short tile[16 * 520];
#pragma unroll
    for (int pass = 0; pass < 8; pass++) {
        int idx = pass * 256 + tid;
        int row = idx >> 7, c4 = idx & 127;
        float4 v = *(const float4*)(x + ((size_t)(m * 16 + row) * S_ + t) * I_ + c4 * 4);
        unsigned short* d = &tile[row * 520 + c4 * 4];
        d[0] = f2bf(v.x); d[1] = f2bf(v.y); d[2] = f2bf(v.z); d[3] = f2bf(v.w);
    }
    __syncthreads();
#pragma unroll
    for (int pass = 0; pass < 4; pass++) {
        int chunk = pass * 256 + tid;
        int ks = chunk >> 6, lane = chunk & 63;
        int c = lane & 15, kq = lane >> 4;
        int k = ks * 32 + kq * 8;
        u16x8 v = *(const u16x8*)(&tile[c * 520 + k]);
        *(u16x8*)(Gx + (((size_t)(t * 8 + m) * 16 + ks) * 64 + lane) * 8) = v;
    }
}

// sx[t*128+b] = x[b][t][:] . Wa_x  (fp32 exact)
__global__ __launch_bounds__(256) void sx_kernel(const float* __restrict__ x,
                                                 const float* __restrict__ Watt,
                                                 float* __restrict__ sx) {
    int t = blockIdx.x;
    int w = threadIdx.x >> 6, lane = threadIdx.x & 63;
    float4 wa0 = *(const float4*)(Watt + lane * 8);
    float4 wa1 = *(const float4*)(Watt + lane * 8 + 4);
    for (int i = 0; i < 32; i++) {
        int b = w * 32 + i;
        const float4* xp = (const float4*)(x + ((size_t)b * S_ + t) * I_ + lane * 8);
        float4 a0 = xp[0], a1 = xp[1];
        float s = a0.x * wa0.x + a0.y * wa0.y + a0.z * wa0.z + a0.w * wa0.w
                + a1.x * wa1.x + a1.y * wa1.y + a1.z * wa1.z + a1.w * wa1.w;
#pragma unroll
        for (int off = 1; off < 64; off <<= 1) s += __shfl_xor(s, off, 64);
        if (lane == 0) sx[t * 128 + b] = s;
    }
}

// ---------------------------------------------------------------------------
// Phase A: G[t] = x_t @ W_ih.T. Gfrag layout per (t,p,m): 192 u16, compact
// C-fragment: index (quad*12 + c)*4 + r for cols c<12.
// ---------------------------------------------------------------------------
__global__ __launch_bounds__(256) void phase_a(const unsigned short* __restrict__ Gx,
                                               const unsigned short* __restrict__ WihP,
                                               unsigned short* __restrict__ Gfrag) {
    int bid = blockIdx.x;                 // 8192 = 256 t * 32 pc
    int t = bid >> 5, pc = bid & 31;
    int tid = threadIdx.x, w = tid >> 6, lane = tid & 63;
    int quad = lane >> 4, c = lane & 15;

    f32x4 acc[2][8];
#pragma unroll
    for (int mi = 0; mi < 2; mi++)
#pragma unroll
        for (int n8 = 0; n8 < 8; n8++) acc[mi][n8] = (f32x4){0.f, 0.f, 0.f, 0.f};

    for (int ks = 0; ks < 16; ks++) {
        bf16x8 af[2];
#pragma unroll
        for (int mi = 0; mi < 2; mi++)
            af[mi] = *(const bf16x8*)(Gx + (((size_t)(t * 8 + w * 2 + mi) * 16 + ks) * 64 + lane) * 8);
        bf16x8 bf[8];
#pragma unroll
        for (int n8 = 0; n8 < 8; n8++)
            bf[n8] = *(const bf16x8*)(WihP + ((((size_t)(pc * 8 + n8)) * 16 + ks) * 64 + lane) * 8);
#pragma unroll
        for (int mi = 0; mi < 2; mi++)
#pragma unroll
            for (int n8 = 0; n8 < 8; n8++)
                acc[mi][n8] = __builtin_amdgcn_mfma_f32_16x16x32_bf16(af[mi], bf[n8], acc[mi][n8], 0, 0, 0);
    }

    if (c < 12) {
#pragma unroll
        for (int mi = 0; mi < 2; mi++) {
            int m = w * 2 + mi;
#pragma unroll
            for (int n8 = 0; n8 < 8; n8++) {
                int p = pc * 8 + n8;
                uint2 vv;
                vv.x = (unsigned)f2bf(acc[mi][n8][0]) | ((unsigned)f2bf(acc[mi][n8][1]) << 16);
                vv.y = (unsigned)f2bf(acc[mi][n8][2]) | ((unsigned)f2bf(acc[mi][n8][3]) << 16);
                *(uint2*)(Gfrag + ((size_t)(t * 256 + p) * 8 + m) * 192 + (size_t)(quad * 12 + c) * 4) = vv;
            }
        }
    }
}

// ---------------------------------------------------------------------------
// Persistent recurrence. 256 blocks x 512 thr (8 waves, wave w = m-tile w).
// Block p owns h-cols 4p..4p+3. Whh hi+lo resident in LDS (64 KB).
// Barrier: RELEASE fetch_add once, RELAXED spin, ONE acquire fence.
// ---------------------------------------------------------------------------
__global__ __launch_bounds__(512, 4) void gru_persist(
        const unsigned short* __restrict__ Gfrag,
        const float* __restrict__ sx,
        const unsigned short* __restrict__ WhhHiP,
        const unsigned short* __restrict__ WhhLoP,
        unsigned short* __restrict__ H0hi, unsigned short* __restrict__ H0lo,
        unsigned short* __restrict__ H1hi, unsigned short* __restrict__ H1lo,
        const float* __restrict__ Watt, const float* __restrict__ batt,
        const float* __restrict__ bih, const float* __restrict__ bhh,
        float* __restrict__ out, unsigned* __restrict__ bar) {
    int p = blockIdx.x;
    int tid = threadIdx.x, w = tid >> 6, lane = tid & 63;
    int quad = lane >> 4, c = lane & 15, cl = c & 3;

    __shared__ unsigned short bhi[16384];    // 32 KB [ks 32][lane 64][8]
    __shared__ unsigned short blo[16384];    // 32 KB
    __shared__ float wa_lds[1024];
    __shared__ float sh_lds[128];
    __shared__ float score_lds[128];

    {
        const uint4* s0 = (const uint4*)(WhhHiP + (size_t)p * 16384);
        uint4* d0 = (uint4*)bhi;
        for (int i = tid; i < 2048; i += 512) d0[i] = s0[i];
        const uint4* s1 = (const uint4*)(WhhLoP + (size_t)p * 16384);
        uint4* d1 = (uint4*)blo;
        for (int i = tid; i < 2048; i += 512) d1[i] = s1[i];
        for (int i = tid; i < 1024; i += 512) wa_lds[i] = Watt[I_ + i];
    }
    float ba = batt[0];
    int j = p * 4 + cl;
    float bihr = bih[j], bihz = bih[H_ + j], bihn = bih[2 * H_ + j];
    float bhhr = bhh[j], bhhz = bhh[H_ + j], bhhn = bhh[2 * H_ + j];
    __syncthreads();

    unsigned short* curHi = H0hi; unsigned short* curLo = H0lo;
    unsigned short* nxtHi = H1hi; unsigned short* nxtLo = H1lo;
    float hprev[4] = {0.f, 0.f, 0.f, 0.f};

    // prefetch step-0 G fragment + sx
    uint2 gd; gd.x = 0u; gd.y = 0u;
    if (c < 12) gd = *(const uint2*)(Gfrag + ((size_t)p * 8 + w) * 192 + (size_t)(quad * 12 + c) * 4);
    float sxv = (tid < 128) ? sx[tid] : 0.f;

    for (int t = 0; t < S_; t++) {
        // ---- K-loop: gh = h @ Whh.T (3-product bf16 split) + sh dot ----
        f32x4 acc0 = (f32x4){0.f, 0.f, 0.f, 0.f};
        f32x4 acc1 = (f32x4){0.f, 0.f, 0.f, 0.f};
        float shp = 0.f;
#pragma unroll 2
        for (int ks = 0; ks < 32; ks++) {
            size_t aoff = (((size_t)w * 32 + ks) * 64 + lane) * 8;
            bf16x8 ah = *(const bf16x8*)(curHi + aoff);
            bf16x8 al = *(const bf16x8*)(curLo + aoff);
            bf16x8 bh = *(const bf16x8*)(bhi + ((size_t)ks * 64 + lane) * 8);
            bf16x8 bl = *(const bf16x8*)(blo + ((size_t)ks * 64 + lane) * 8);
            float4 w0 = *(const float4*)(wa_lds + ks * 32 + quad * 8);
            float4 w1 = *(const float4*)(wa_lds + ks * 32 + quad * 8 + 4);
            shp += (float)ah[0] * w0.x + (float)ah[1] * w0.y + (float)ah[2] * w0.z + (float)ah[3] * w0.w
                 + (float)ah[4] * w1.x + (float)ah[5] * w1.y + (float)ah[6] * w1.z + (float)ah[7] * w1.w;
            if (ks & 1) {
                acc1 = __builtin_amdgcn_mfma_f32_16x16x32_bf16(ah, bh, acc1, 0, 0, 0);
                acc1 = __builtin_amdgcn_mfma_f32_16x16x32_bf16(al, bh, acc1, 0, 0, 0);
                acc1 = __builtin_amdgcn_mfma_f32_16x16x32_bf16(ah, bl, acc1, 0, 0, 0);
            } else {
                acc0 = __builtin_amdgcn_mfma_f32_16x16x32_bf16(ah, bh, acc0, 0, 0, 0);
                acc0 = __builtin_amdgcn_mfma_f32_16x16x32_bf16(al, bh, acc0, 0, 0, 0);
                acc0 = __builtin_amdgcn_mfma_f32_16x16x32_bf16(ah, bl, acc0, 0, 0, 0);
            }
        }
        f32x4 acc;
#pragma unroll
        for (int r = 0; r < 4; r++) acc[r] = acc0[r] + acc1[r];

        // ---- sh reduce + score ----
        shp += __shfl_xor(shp, 16, 64);
        shp += __shfl_xor(shp, 32, 64);
        if (lane < 16) sh_lds[w * 16 + lane] = shp;
        __syncthreads();
        if (tid < 128) score_lds[tid] = sh_lds[tid] + sxv + ba;
        __syncthreads();

        // ---- softmax stats (per wave, redundant) ----
        float s0 = score_lds[lane], s1 = score_lds[lane + 64];
        float mx = fmaxf(s0, s1);
#pragma unroll
        for (int off = 1; off < 64; off <<= 1) mx = fmaxf(mx, __shfl_xor(mx, off, 64));
        float pe = __expf(s0 - mx) + __expf(s1 - mx);
#pragma unroll
        for (int off = 1; off < 64; off <<= 1) pe += __shfl_xor(pe, off, 64);
        float rden = 1.f / pe;

        // ---- gates (C layout: col=lane&15, row=quad*4+r) ----
        uint2 gdz, gdn;
        gdz.x = (unsigned)__shfl_xor((int)gd.x, 4, 64);
        gdz.y = (unsigned)__shfl_xor((int)gd.y, 4, 64);
        gdn.x = (unsigned)__shfl_xor((int)gd.x, 8, 64);
        gdn.y = (unsigned)__shfl_xor((int)gd.y, 8, 64);
#pragma unroll
        for (int r = 0; r < 4; r++) {
            int b = w * 16 + quad * 4 + r;
            float att = __expf(score_lds[b] - mx) * rden;
            float ghr = acc[r];
            float ghz = __shfl_xor(ghr, 4, 64);
            float ghn = __shfl_xor(ghr, 8, 64);
            int sh16 = (r & 1) * 16;
            float Gr = bf2f((unsigned short)(((r < 2) ? gd.x : gd.y) >> sh16));
            float Gz = bf2f((unsigned short)(((r < 2) ? gdz.x : gdz.y) >> sh16));
            float Gn = bf2f((unsigned short)(((r < 2) ? gdn.x : gdn.y) >> sh16));
            float rg = 1.f / (1.f + __expf(-(att * Gr + bihr + ghr + bhhr)));
            float zg = 1.f / (1.f + __expf(-(att * Gz + bihz + ghz + bhhz)));
            float ng = tanhf(att * Gn + bihn + rg * (ghn + bhhn));
            float hnew = (1.f - zg) * ng + zg * hprev[r];
            hprev[r] = hnew;
            if (c < 4) {
                out[((size_t)b * S_ + t) * H_ + j] = hnew;
                unsigned short hi16 = f2bf(hnew);
                unsigned short lo16 = f2bf(hnew - bf2f(hi16));
                int kk = j & 31, ksh = j >> 5, qh = kk >> 3, jj = kk & 7;
                size_t ha = (((size_t)w * 32 + ksh) * 64 + (quad * 4 + r) + 16 * qh) * 8 + jj;
                nxtHi[ha] = hi16; nxtLo[ha] = lo16;
                if (t == S_ - 1) out[(size_t)B_ * S_ * H_ + (size_t)b * H_ + j] = hnew;
            }
        }

        if (t + 1 < S_) {
            // prefetch next step's constants (overlaps barrier wait)
            if (c < 12)
                gd = *(const uint2*)(Gfrag + ((size_t)((t + 1) * 256 + p) * 8 + w) * 192 + (size_t)(quad * 12 + c) * 4);
            if (tid < 128) sxv = sx[(t + 1) * 128 + tid];

            // ---- grid barrier: one release add, relaxed spin, one acquire ----
            __syncthreads();                 // drains vmcnt (stores issued)
            if (tid == 0) {
                __hip_atomic_fetch_add(bar + (p & 7) * 32, 1u,
                                       __ATOMIC_RELEASE, __HIP_MEMORY_SCOPE_AGENT);
                unsigned tgt = (unsigned)(t + 1) * 32u;   // 256 blocks / 8 counters
                for (int i = 0; i < 8; i++) {
                    while (__hip_atomic_load(bar + i * 32,
                                             __ATOMIC_RELAXED, __HIP_MEMORY_SCOPE_AGENT) < tgt)
                        __builtin_amdgcn_s_sleep(1);
                }
                __builtin_amdgcn_fence(__ATOMIC_ACQUIRE, "agent");
            }
            __syncthreads();

            unsigned short* th = curHi; curHi = nxtHi; nxtHi = th;
            unsigned short* tl = curLo; curLo = nxtLo; nxtLo = tl;
        }
    }
}

// ---------------------------------------------------------------------------
extern "C" void kernel_launch(void* const* d_in, const int* in_sizes, int n_in,
                              void* d_out, int out_size, void* d_ws, size_t ws_size,
                              hipStream_t stream) {
    (void)in_sizes; (void)n_in; (void)out_size; (void)ws_size;
    const float* x    = (const float*)d_in[0];
    const float* Watt = (const float*)d_in[1];
    const float* batt = (const float*)d_in[2];
    const float* Wih  = (const float*)d_in[3];
    const float* Whh  = (const float*)d_in[4];
    const float* bih  = (const float*)d_in[5];
    const float* bhh  = (const float*)d_in[6];
    float* out = (float*)d_out;

    char* ws = (char*)d_ws;
    size_t off = 0;
    unsigned short* Gfrag  = (unsigned short*)(ws + off); off += 201326592ULL; // 256*256*8*192*2
    unsigned short* Gx     = (unsigned short*)(ws + off); off += 33554432ULL;
    unsigned short* WihP   = (unsigned short*)(ws + off); off += 4194304ULL;
    unsigned short* WhhHiP = (unsigned short*)(ws + off); off += 8388608ULL;
    unsigned short* WhhLoP = (unsigned short*)(ws + off); off += 8388608ULL;
    float*          sx     = (float*)(ws + off);          off += 131072ULL;
    unsigned short* H0hi   = (unsigned short*)(ws + off); off += 262144ULL;
    unsigned short* H0lo   = (unsigned short*)(ws + off); off += 262144ULL;
    unsigned short* H1hi   = (unsigned short*)(ws + off); off += 262144ULL;
    unsigned short* H1lo   = (unsigned short*)(ws + off); off += 262144ULL;
    unsigned*       bar    = (unsigned*)(ws + off);       off += 1024ULL;

    hipMemsetAsync(H0hi, 0, 524288, stream);   // H0hi + H0lo (adjacent)
    hipMemsetAsync(bar, 0, 1024, stream);
    pack_wih<<<1024, 256, 0, stream>>>(Wih, WihP);
    pack_whh<<<2048, 256, 0, stream>>>(Whh, WhhHiP, WhhLoP);
    pack_x<<<2048, 256, 0, stream>>>(x, Gx);
    sx_kernel<<<256, 256, 0, stream>>>(x, Watt, sx);
    phase_a<<<8192, 256, 0, stream>>>(Gx, WihP, Gfrag);
    gru_persist<<<256, 512, 0, stream>>>(Gfrag, sx, WhhHiP, WhhLoP,
                                         H0hi, H0lo, H1hi, H1lo,
                                         Watt, batt, bih, bhh, out, bar);
}

// Round 5
// 4577.093 us; speedup vs baseline: 1.7454x; 1.7454x over previous
//
#include <hip/hip_runtime.h>
#include <hip/hip_bf16.h>

#define B_ 128
#define S_ 256
#define I_ 512
#define H_ 1024

typedef float  f32x4  __attribute__((ext_vector_type(4)));
typedef __bf16 bf16x8 __attribute__((ext_vector_type(8)));
typedef unsigned short u16x8 __attribute__((ext_vector_type(8)));
typedef unsigned int   u32x4 __attribute__((ext_vector_type(4)));

__device__ __forceinline__ unsigned short f2bf(float f) {
    unsigned u = __float_as_uint(f);
    unsigned r = (u + 0x7fffu + ((u >> 16) & 1u)) >> 16;   // RNE
    return (unsigned short)r;
}
__device__ __forceinline__ float bf2f(unsigned short s) {
    return __uint_as_float(((unsigned)s) << 16);
}

// ---------------------------------------------------------------------------
// Column mapping (4 h-cols per p, 256 p-groups): B/C tile col c:
//   c 0-3 -> r-gate row p*4+c ; c 4-7 -> z-gate H+... ; c 8-11 -> n-gate 2H+...
//   c 12-15 -> zero pad.  (R3-verified numerically.)
// ---------------------------------------------------------------------------

// Pack W_ih [3H, I] into per-colgroup B-frag order: [p 256][ks 16][lane 64][8]
__global__ __launch_bounds__(256) void pack_wih(const float* __restrict__ W,
                                                unsigned short* __restrict__ out) {
    int gid = blockIdx.x * 256 + threadIdx.x;        // 262144 total
    int lane = gid & 63, ks = (gid >> 6) & 15, p = gid >> 10;
    int c = lane & 15, quad = lane >> 4;
    int k = ks * 32 + quad * 8;
    int n = 0; bool valid = true;
    if (c < 4) n = p * 4 + c;
    else if (c < 8) n = H_ + p * 4 + (c - 4);
    else if (c < 12) n = 2 * H_ + p * 4 + (c - 8);
    else valid = false;
    const float* src = W + (size_t)n * I_ + k;
    u16x8 v;
#pragma unroll
    for (int jj = 0; jj < 8; jj++) v[jj] = valid ? f2bf(src[jj]) : (unsigned short)0;
    *(u16x8*)(out + (size_t)gid * 8) = v;
}

// Pack W_hh [3H, H] hi/lo into B-frag order: [p 256][ks 32][lane 64][8]
__global__ __launch_bounds__(256) void pack_whh(const float* __restrict__ W,
                                                unsigned short* __restrict__ hi,
                                                unsigned short* __restrict__ lo) {
    int gid = blockIdx.x * 256 + threadIdx.x;        // 524288 total
    int lane = gid & 63, ks = (gid >> 6) & 31, p = gid >> 11;
    int c = lane & 15, quad = lane >> 4;
    int k = ks * 32 + quad * 8;
    int n = 0; bool valid = true;
    if (c < 4) n = p * 4 + c;
    else if (c < 8) n = H_ + p * 4 + (c - 4);
    else if (c < 12) n = 2 * H_ + p * 4 + (c - 8);
    else valid = false;
    const float* src = W + (size_t)n * H_ + k;
    u16x8 vh, vl;
#pragma unroll
    for (int jj = 0; jj < 8; jj++) {
        float f = valid ? src[jj] : 0.f;
        unsigned short h16 = f2bf(f);
        unsigned short l16 = f2bf(f - bf2f(h16));
        vh[jj] = valid ? h16 : (unsigned short)0;
        vl[jj] = valid ? l16 : (unsigned short)0;
    }
    *(u16x8*)(hi + (size_t)gid * 8) = vh;
    *(u16x8*)(lo + (size_t)gid * 8) = vl;
}

// Pack x into A-frag bf16 layout via LDS transpose: [t][m 8][ks 16][lane 64][8]
__global__ __launch_bounds__(256) void pack_x(const float* __restrict__ x,
                                              unsigned short* __restrict__ Gx) {
    int bid = blockIdx.x;                 // 2048 = 256 t * 8 m
    int t = bid >> 3, m = bid & 7;
    int tid = threadIdx.x;
    __shared__ unsigned short tile[16 * 520];
#pragma unroll
    for (int pass = 0; pass < 8; pass++) {
        int idx = pass * 256 + tid;
        int row = idx >> 7, c4 = idx & 127;
        float4 v = *(const float4*)(x + ((size_t)(m * 16 + row) * S_ + t) * I_ + c4 * 4);
        unsigned short* d = &tile[row * 520 + c4 * 4];
        d[0] = f2bf(v.x); d[1] = f2bf(v.y); d[2] = f2bf(v.z); d[3] = f2bf(v.w);
    }
    __syncthreads();
#pragma unroll
    for (int pass = 0; pass < 4; pass++) {
        int chunk = pass * 256 + tid;
        int ks = chunk >> 6, lane = chunk & 63;
        int c = lane & 15, kq = lane >> 4;
        int k = ks * 32 + kq * 8;
        u16x8 v = *(const u16x8*)(&tile[c * 520 + k]);
        *(u16x8*)(Gx + (((size_t)(t * 8 + m) * 16 + ks) * 64 + lane) * 8) = v;
    }
}

// sx[t*128+b] = x[b][t][:] . Wa_x  (fp32 exact)
__global__ __launch_bounds__(256) void sx_kernel(const float* __restrict__ x,
                                                 const float* __restrict__ Watt,
                                                 float* __restrict__ sx) {
    int t = blockIdx.x;
    int w = threadIdx.x >> 6, lane = threadIdx.x & 63;
    float4 wa0 = *(const float4*)(Watt + lane * 8);
    float4 wa1 = *(const float4*)(Watt + lane * 8 + 4);
    for (int i = 0; i < 32; i++) {
        int b = w * 32 + i;
        const float4* xp = (const float4*)(x + ((size_t)b * S_ + t) * I_ + lane * 8);
        float4 a0 = xp[0], a1 = xp[1];
        float s = a0.x * wa0.x + a0.y * wa0.y + a0.z * wa0.z + a0.w * wa0.w
                + a1.x * wa1.x + a1.y * wa1.y + a1.z * wa1.z + a1.w * wa1.w;
#pragma unroll
        for (int off = 1; off < 64; off <<= 1) s += __shfl_xor(s, off, 64);
        if (lane == 0) sx[t * 128 + b] = s;
    }
}

__device__ __forceinline__ void unpack_hilo(u32x4 q0, u32x4 q1,
                                            bf16x8& ah, bf16x8& al) {
    u32x4 hv, lv;
    hv[0] = (q0[0] & 0xffffu) | (q0[1] << 16);
    hv[1] = (q0[2] & 0xffffu) | (q0[3] << 16);
    hv[2] = (q1[0] & 0xffffu) | (q1[1] << 16);
    hv[3] = (q1[2] & 0xffffu) | (q1[3] << 16);
    lv[0] = (q0[0] >> 16) | (q0[1] & 0xffff0000u);
    lv[1] = (q0[2] >> 16) | (q0[3] & 0xffff0000u);
    lv[2] = (q1[0] >> 16) | (q1[1] & 0xffff0000u);
    lv[3] = (q1[2] >> 16) | (q1[3] & 0xffff0000u);
    ah = __builtin_bit_cast(bf16x8, hv);
    al = __builtin_bit_cast(bf16x8, lv);
}

// ---------------------------------------------------------------------------
// Persistent recurrence. 256 blocks x 512 thr (wave w = m-tile w). Block p
// owns h-cols 4p..4p+3. Whh hi+lo (64 KB) + Wih col-slice (16 KB) in LDS.
// gi computed per step via MFMA on raw x-fragments, att applied to fp32 C rows.
// H chain: fresh u32(hi|lo<<16) buffer per step, sc0+sc1 write-through stores,
// normal cached loads (no stale lines possible), fence-free relaxed barrier.
// H element index (u32): ((m*32 + ks)*64 + lane)*8 + j ; lane = 16*q' + row15,
// so C-row r increments lane by 1 => +8 u32 (R4 bug: wrote +64).
// ---------------------------------------------------------------------------
__global__ __launch_bounds__(512) void gru_persist(
        const unsigned short* __restrict__ Gx,
        const float* __restrict__ sx,
        const unsigned short* __restrict__ WihP,
        const unsigned short* __restrict__ WhhHiP,
        const unsigned short* __restrict__ WhhLoP,
        unsigned* __restrict__ Hc,
        const float* __restrict__ Watt, const float* __restrict__ batt,
        const float* __restrict__ bih, const float* __restrict__ bhh,
        float* __restrict__ out, unsigned* __restrict__ bar) {
    int p = blockIdx.x;
    int tid = threadIdx.x, w = tid >> 6, lane = tid & 63;
    int quad = lane >> 4, c = lane & 15, cl = c & 3;

    __shared__ unsigned short bhi[16384];     // 32 KB [ks 32][lane 64][8]
    __shared__ unsigned short blo[16384];     // 32 KB
    __shared__ unsigned short wih_lds[8192];  // 16 KB [ks 16][lane 64][8]
    __shared__ float wa_lds[1024];
    __shared__ float sh_lds[128];
    __shared__ float score_lds[128];

    {
        const uint4* s0 = (const uint4*)(WhhHiP + (size_t)p * 16384);
        uint4* d0 = (uint4*)bhi;
        for (int i = tid; i < 2048; i += 512) d0[i] = s0[i];
        const uint4* s1 = (const uint4*)(WhhLoP + (size_t)p * 16384);
        uint4* d1 = (uint4*)blo;
        for (int i = tid; i < 2048; i += 512) d1[i] = s1[i];
        const uint4* s2 = (const uint4*)(WihP + (size_t)p * 8192);
        uint4* d2 = (uint4*)wih_lds;
        for (int i = tid; i < 1024; i += 512) d2[i] = s2[i];
        for (int i = tid; i < 1024; i += 512) wa_lds[i] = Watt[I_ + i];
    }
    float ba = batt[0];
    int j = p * 4 + cl;
    float bihr = bih[j], bihz = bih[H_ + j], bihn = bih[2 * H_ + j];
    float bhhr = bhh[j], bhhz = bhh[H_ + j], bhhn = bhh[2 * H_ + j];
    __syncthreads();

    float hprev[4] = {0.f, 0.f, 0.f, 0.f};
    // h-store address components (lane c<4): k32 = (p&7)*4+cl
    int k32 = (p & 7) * 4 + cl;
    size_t hstore_idx = (((size_t)w * 32 + (p >> 3)) * 64
                         + (size_t)(quad * 4) + 16 * (k32 >> 3)) * 8 + (k32 & 7);

    for (int t = 0; t < S_; t++) {
        const unsigned* hc = Hc + (size_t)t * 131072;
        unsigned* hn = Hc + (size_t)(t + 1) * 131072;
        float sxv = (tid < 128) ? sx[t * 128 + tid] : 0.f;

        f32x4 accg = (f32x4){0.f, 0.f, 0.f, 0.f};
        f32x4 acc0 = (f32x4){0.f, 0.f, 0.f, 0.f};
        f32x4 acc1 = (f32x4){0.f, 0.f, 0.f, 0.f};
        float shp = 0.f;

        const unsigned* abase = hc + ((size_t)w * 32 * 64 + lane) * 8;
        // per-ks stride in u32: 64*8 = 512
        u32x4 q0 = *(const u32x4*)(abase);
        u32x4 q1 = *(const u32x4*)(abase + 4);
#pragma unroll 2
        for (int ks = 0; ks < 32; ks++) {
            u32x4 n0 = (u32x4){0u, 0u, 0u, 0u}, n1 = (u32x4){0u, 0u, 0u, 0u};
            if (ks < 31) {
                n0 = *(const u32x4*)(abase + (size_t)(ks + 1) * 512);
                n1 = *(const u32x4*)(abase + (size_t)(ks + 1) * 512 + 4);
            }
            bf16x8 ah, al;
            unpack_hilo(q0, q1, ah, al);
            bf16x8 bh = *(const bf16x8*)(bhi + ((size_t)ks * 64 + lane) * 8);
            bf16x8 bl = *(const bf16x8*)(blo + ((size_t)ks * 64 + lane) * 8);
            if (ks < 16) {
                bf16x8 xa = *(const bf16x8*)(Gx + ((((size_t)t * 8 + w) * 16 + ks) * 64 + lane) * 8);
                bf16x8 wb = *(const bf16x8*)(wih_lds + ((size_t)ks * 64 + lane) * 8);
                accg = __builtin_amdgcn_mfma_f32_16x16x32_bf16(xa, wb, accg, 0, 0, 0);
            }
            float4 w0 = *(const float4*)(wa_lds + ks * 32 + quad * 8);
            float4 w1 = *(const float4*)(wa_lds + ks * 32 + quad * 8 + 4);
            shp += (float)ah[0] * w0.x + (float)ah[1] * w0.y + (float)ah[2] * w0.z + (float)ah[3] * w0.w
                 + (float)ah[4] * w1.x + (float)ah[5] * w1.y + (float)ah[6] * w1.z + (float)ah[7] * w1.w;
            if (ks & 1) {
                acc1 = __builtin_amdgcn_mfma_f32_16x16x32_bf16(ah, bh, acc1, 0, 0, 0);
                acc1 = __builtin_amdgcn_mfma_f32_16x16x32_bf16(al, bh, acc1, 0, 0, 0);
                acc1 = __builtin_amdgcn_mfma_f32_16x16x32_bf16(ah, bl, acc1, 0, 0, 0);
            } else {
                acc0 = __builtin_amdgcn_mfma_f32_16x16x32_bf16(ah, bh, acc0, 0, 0, 0);
                acc0 = __builtin_amdgcn_mfma_f32_16x16x32_bf16(al, bh, acc0, 0, 0, 0);
                acc0 = __builtin_amdgcn_mfma_f32_16x16x32_bf16(ah, bl, acc0, 0, 0, 0);
            }
            q0 = n0; q1 = n1;
        }

        // ---- sh reduce + score ----
        shp += __shfl_xor(shp, 16, 64);
        shp += __shfl_xor(shp, 32, 64);
        if (lane < 16) sh_lds[w * 16 + lane] = shp;
        __syncthreads();
        if (tid < 128) score_lds[tid] = sh_lds[tid] + sxv + ba;
        __syncthreads();

        // ---- softmax stats (per wave, redundant) ----
        float s0 = score_lds[lane], s1 = score_lds[lane + 64];
        float mx = fmaxf(s0, s1);
#pragma unroll
        for (int off = 1; off < 64; off <<= 1) mx = fmaxf(mx, __shfl_xor(mx, off, 64));
        float pe = __expf(s0 - mx) + __expf(s1 - mx);
#pragma unroll
        for (int off = 1; off < 64; off <<= 1) pe += __shfl_xor(pe, off, 64);
        float rden = 1.f / pe;

        // ---- gates (C layout: col=lane&15, row=quad*4+r) ----
        f32x4 gh;
#pragma unroll
        for (int r = 0; r < 4; r++) gh[r] = acc0[r] + acc1[r];
#pragma unroll
        for (int r = 0; r < 4; r++) {
            int b = w * 16 + quad * 4 + r;
            float att = __expf(score_lds[b] - mx) * rden;
            float ghr = gh[r];
            float ghz = __shfl_xor(ghr, 4, 64);
            float ghn = __shfl_xor(ghr, 8, 64);
            float gir = accg[r];
            float giz = __shfl_xor(gir, 4, 64);
            float gin = __shfl_xor(gir, 8, 64);
            float rg = 1.f / (1.f + __expf(-(att * gir + bihr + ghr + bhhr)));
            float zg = 1.f / (1.f + __expf(-(att * giz + bihz + ghz + bhhz)));
            float ng = tanhf(att * gin + bihn + rg * (ghn + bhhn));
            float hnew = (1.f - zg) * ng + zg * hprev[r];
            hprev[r] = hnew;
            if (c < 4) {
                out[((size_t)b * S_ + t) * H_ + j] = hnew;
                unsigned short hi16 = f2bf(hnew);
                unsigned short lo16 = f2bf(hnew - bf2f(hi16));
                unsigned hval = (unsigned)hi16 | ((unsigned)lo16 << 16);
                unsigned* dst = hn + hstore_idx + (size_t)r * 8;  // +r rows: +1 lane = +8 u32
                asm volatile("global_store_dword %0, %1, off sc0 sc1"
                             :: "v"(dst), "v"(hval) : "memory");
                if (t == S_ - 1) out[(size_t)B_ * S_ * H_ + (size_t)b * H_ + j] = hnew;
            }
        }

        if (t + 1 < S_) {
            // ---- fence-free grid barrier (fresh-buffer coherence) ----
            __syncthreads();     // each wave drains vmcnt -> sc1 stores visible
            if (tid == 0) {
                __hip_atomic_fetch_add(bar + (p & 7) * 32, 1u,
                                       __ATOMIC_RELAXED, __HIP_MEMORY_SCOPE_AGENT);
                unsigned tgt = (unsigned)(t + 1) * 32u;   // 256 blocks / 8 counters
                for (int i = 0; i < 8; i++) {
                    while (__hip_atomic_load(bar + i * 32,
                                             __ATOMIC_RELAXED, __HIP_MEMORY_SCOPE_AGENT) < tgt)
                        __builtin_amdgcn_s_sleep(1);
                }
            }
            __syncthreads();
        }
    }
}

// ---------------------------------------------------------------------------
extern "C" void kernel_launch(void* const* d_in, const int* in_sizes, int n_in,
                              void* d_out, int out_size, void* d_ws, size_t ws_size,
                              hipStream_t stream) {
    (void)in_sizes; (void)n_in; (void)out_size; (void)ws_size;
    const float* x    = (const float*)d_in[0];
    const float* Watt = (const float*)d_in[1];
    const float* batt = (const float*)d_in[2];
    const float* Wih  = (const float*)d_in[3];
    const float* Whh  = (const float*)d_in[4];
    const float* bih  = (const float*)d_in[5];
    const float* bhh  = (const float*)d_in[6];
    float* out = (float*)d_out;

    char* ws = (char*)d_ws;
    size_t off = 0;
    unsigned short* Gx     = (unsigned short*)(ws + off); off += 33554432ULL;   // 32 MB
    unsigned short* WihP   = (unsigned short*)(ws + off); off += 4194304ULL;    // 4 MB
    unsigned short* WhhHiP = (unsigned short*)(ws + off); off += 8388608ULL;    // 8 MB
    unsigned short* WhhLoP = (unsigned short*)(ws + off); off += 8388608ULL;    // 8 MB
    float*          sx     = (float*)(ws + off);          off += 131072ULL;
    unsigned*       Hc     = (unsigned*)(ws + off);       off += 134742016ULL;  // 257 * 512 KB
    unsigned*       bar    = (unsigned*)(ws + off);       off += 1024ULL;

    hipMemsetAsync(Hc, 0, 524288, stream);     // Hc[0] = zeros (h0)
    hipMemsetAsync(bar, 0, 1024, stream);
    pack_wih<<<1024, 256, 0, stream>>>(Wih, WihP);
    pack_whh<<<2048, 256, 0, stream>>>(Whh, WhhHiP, WhhLoP);
    pack_x<<<2048, 256, 0, stream>>>(x, Gx);
    sx_kernel<<<256, 256, 0, stream>>>(x, Watt, sx);
    gru_persist<<<256, 512, 0, stream>>>(Gx, sx, WihP, WhhHiP, WhhLoP, Hc,
                                         Watt, batt, bih, bhh, out, bar);
}